// Round 1
// baseline (838.530 us; speedup 1.0000x reference)
//
#include <hip/hip_runtime.h>

// GCN forward: l2norm -> [GEMM -> SpMM -> ReLU] x3 (last layer no ReLU)
// CSR built on-device each call (histogram + scan + scatter), gather-SpMM (no float atomics).

constexpr int IN_DIM = 256, HD1 = 128, HD2 = 64, OUT_DIM = 32;

// ---------------- L2 normalize (one wave per row, float4 per lane) ----------------
__global__ __launch_bounds__(256) void l2norm_kernel(const float* __restrict__ in,
                                                     float* __restrict__ out, int M) {
    int wave = threadIdx.x >> 6;
    int lane = threadIdx.x & 63;
    int row = blockIdx.x * 4 + wave;
    if (row >= M) return;
    const float4 v = *reinterpret_cast<const float4*>(&in[(size_t)row * IN_DIM + lane * 4]);
    float s = v.x * v.x + v.y * v.y + v.z * v.z + v.w * v.w;
    #pragma unroll
    for (int off = 32; off; off >>= 1) s += __shfl_xor(s, off, 64);
    float scale = 1.0f / sqrtf(fmaxf(s, 1e-12f));
    float4 o{v.x * scale, v.y * scale, v.z * scale, v.w * scale};
    *reinterpret_cast<float4*>(&out[(size_t)row * IN_DIM + lane * 4]) = o;
}

// ---------------- CSR build ----------------
__global__ __launch_bounds__(256) void hist_kernel(const int* __restrict__ row,
                                                   int* __restrict__ counts, int E) {
    int e = blockIdx.x * blockDim.x + threadIdx.x;
    if (e < E) atomicAdd(&counts[row[e]], 1);
}

__global__ __launch_bounds__(1024) void scan_kernel(const int* __restrict__ counts,
                                                    int* __restrict__ row_ptr, int n) {
    constexpr int B = 1024;
    __shared__ int sm[B];
    const int tid = threadIdx.x;
    const int chunk = (n + B - 1) / B;
    const int start = min(tid * chunk, n);
    const int end = min(start + chunk, n);
    int s = 0;
    for (int i = start; i < end; ++i) s += counts[i];
    sm[tid] = s;
    __syncthreads();
    #pragma unroll
    for (int off = 1; off < B; off <<= 1) {
        int v = (tid >= off) ? sm[tid - off] : 0;
        __syncthreads();
        sm[tid] += v;
        __syncthreads();
    }
    int run = (tid > 0) ? sm[tid - 1] : 0;
    for (int i = start; i < end; ++i) { row_ptr[i] = run; run += counts[i]; }
    if (tid == B - 1) row_ptr[n] = sm[B - 1];
}

__global__ __launch_bounds__(256) void scatter_kernel(const int* __restrict__ row,
                                                      const int* __restrict__ col,
                                                      const float* __restrict__ val,
                                                      const int* __restrict__ row_ptr,
                                                      int* __restrict__ row_cur,
                                                      int2* __restrict__ pairs, int E) {
    int e = blockIdx.x * blockDim.x + threadIdx.x;
    if (e < E) {
        int r = row[e];
        int pos = row_ptr[r] + atomicAdd(&row_cur[r], 1);
        pairs[pos] = make_int2(col[e], __float_as_int(val[e]));
    }
}

// ---------------- fp32 register-tiled GEMM: C[M,N] = A[M,K] @ B[K,N] ----------------
template <int BM, int BN, int BK, int TM, int TN>
__global__ __launch_bounds__((BM / TM) * (BN / TN)) void gemm_f32(
    const float* __restrict__ A, const float* __restrict__ B, float* __restrict__ C,
    int M, int K, int N) {
    constexpr int THREADS = (BM / TM) * (BN / TN);
    __shared__ float As[BK][BM + 4];
    __shared__ float Bs[BK][BN + 4];
    const int tid = threadIdx.x;
    const int tcol = tid % (BN / TN);
    const int trow = tid / (BN / TN);
    const int row0 = blockIdx.x * BM;
    float acc[TM][TN] = {};
    for (int k0 = 0; k0 < K; k0 += BK) {
        for (int i = tid * 4; i < BM * BK; i += THREADS * 4) {
            int m = i / BK, k = i % BK;
            float4 v = {0.f, 0.f, 0.f, 0.f};
            if (row0 + m < M)
                v = *reinterpret_cast<const float4*>(&A[(size_t)(row0 + m) * K + k0 + k]);
            As[k + 0][m] = v.x; As[k + 1][m] = v.y; As[k + 2][m] = v.z; As[k + 3][m] = v.w;
        }
        for (int i = tid * 4; i < BK * BN; i += THREADS * 4) {
            int k = i / BN, n = i % BN;
            *reinterpret_cast<float4*>(&Bs[k][n]) =
                *reinterpret_cast<const float4*>(&B[(size_t)(k0 + k) * N + n]);
        }
        __syncthreads();
        #pragma unroll
        for (int k = 0; k < BK; ++k) {
            float a[TM], b[TN];
            #pragma unroll
            for (int i = 0; i < TM; i += 4)
                *reinterpret_cast<float4*>(&a[i]) =
                    *reinterpret_cast<const float4*>(&As[k][trow * TM + i]);
            #pragma unroll
            for (int j = 0; j < TN; j += 4)
                *reinterpret_cast<float4*>(&b[j]) =
                    *reinterpret_cast<const float4*>(&Bs[k][tcol * TN + j]);
            #pragma unroll
            for (int i = 0; i < TM; ++i)
                #pragma unroll
                for (int j = 0; j < TN; ++j) acc[i][j] = fmaf(a[i], b[j], acc[i][j]);
        }
        __syncthreads();
    }
    #pragma unroll
    for (int i = 0; i < TM; ++i) {
        int r = row0 + trow * TM + i;
        if (r < M) {
            #pragma unroll
            for (int j = 0; j < TN; j += 4)
                *reinterpret_cast<float4*>(&C[(size_t)r * N + tcol * TN + j]) =
                    *reinterpret_cast<const float4*>(&acc[i][j]);
        }
    }
}

// ---------------- CSR SpMM: out[r,:] = sum_j val_j * H[col_j,:], optional ReLU ----------------
template <int D, bool RELU>
__global__ __launch_bounds__(256) void spmm_csr(const int* __restrict__ row_ptr,
                                                const int2* __restrict__ pairs,
                                                const float* __restrict__ H,
                                                float* __restrict__ out, int M) {
    constexpr int TPR = D / 4;                 // threads per row (float4 each)
    const int rpb = 256 / TPR;                 // rows per block
    const int lg = threadIdx.x % TPR;
    const int rloc = threadIdx.x / TPR;
    int r = blockIdx.x * rpb + rloc;
    if (r >= M) return;
    const int jb = row_ptr[r], je = row_ptr[r + 1];
    float4 acc = {0.f, 0.f, 0.f, 0.f};
    for (int j = jb; j < je; ++j) {
        int2 p = pairs[j];
        float v = __int_as_float(p.y);
        const float4 h = *reinterpret_cast<const float4*>(&H[(size_t)p.x * D + lg * 4]);
        acc.x = fmaf(v, h.x, acc.x);
        acc.y = fmaf(v, h.y, acc.y);
        acc.z = fmaf(v, h.z, acc.z);
        acc.w = fmaf(v, h.w, acc.w);
    }
    if (RELU) {
        acc.x = fmaxf(acc.x, 0.f); acc.y = fmaxf(acc.y, 0.f);
        acc.z = fmaxf(acc.z, 0.f); acc.w = fmaxf(acc.w, 0.f);
    }
    *reinterpret_cast<float4*>(&out[(size_t)r * D + lg * 4]) = acc;
}

extern "C" void kernel_launch(void* const* d_in, const int* in_sizes, int n_in,
                              void* d_out, int out_size, void* d_ws, size_t ws_size,
                              hipStream_t stream) {
    const float* features  = (const float*)d_in[0];
    const float* edge_vals = (const float*)d_in[1];
    const float* W0        = (const float*)d_in[2];
    const float* W1        = (const float*)d_in[3];
    const float* W2        = (const float*)d_in[4];
    const int*   edge_row  = (const int*)d_in[5];
    const int*   edge_col  = (const int*)d_in[6];
    const int M = in_sizes[0] / IN_DIM;   // 100000
    const int E = in_sizes[1];            // 1600000

    char* ws = (char*)d_ws;
    size_t o = 0;
    auto alloc = [&](size_t bytes) {
        size_t r = o;
        o += (bytes + 1023) & ~(size_t)1023;
        return r;
    };
    float* X      = (float*)(ws + alloc((size_t)M * IN_DIM * 4));  // reused as H buffer
    float* T      = (float*)(ws + alloc((size_t)M * HD1 * 4));     // GEMM outputs
    size_t counts_off = alloc((size_t)M * 4);
    int*   counts = (int*)(ws + counts_off);
    int*   rowcur = (int*)(ws + alloc((size_t)M * 4));
    size_t rowptr_off = alloc((size_t)(M + 1) * 4);
    int*   rowptr = (int*)(ws + rowptr_off);
    int2*  pairs  = (int2*)(ws + alloc((size_t)E * 8));
    float* Hbuf = X;
    float* out = (float*)d_out;
    (void)rowcur; (void)ws_size; (void)n_in; (void)out_size;

    // zero counts + rowcur (adjacent in layout)
    hipMemsetAsync(ws + counts_off, 0, rowptr_off - counts_off, stream);

    // CSR build
    hist_kernel<<<(E + 255) / 256, 256, 0, stream>>>(edge_row, counts, E);
    scan_kernel<<<1, 1024, 0, stream>>>(counts, rowptr, M);
    scatter_kernel<<<(E + 255) / 256, 256, 0, stream>>>(edge_row, edge_col, edge_vals,
                                                        rowptr, rowcur, pairs, E);

    // normalize
    l2norm_kernel<<<(M + 3) / 4, 256, 0, stream>>>(features, X, M);

    // layer 1: X @ W0 -> T ; spmm+relu -> Hbuf
    gemm_f32<64, 128, 16, 8, 4><<<(M + 63) / 64, 256, 0, stream>>>(X, W0, T, M, IN_DIM, HD1);
    spmm_csr<128, true><<<(M + 7) / 8, 256, 0, stream>>>(rowptr, pairs, T, Hbuf, M);

    // layer 2: Hbuf @ W1 -> T ; spmm+relu -> Hbuf
    gemm_f32<64, 64, 16, 4, 4><<<(M + 63) / 64, 256, 0, stream>>>(Hbuf, W1, T, M, HD1, HD2);
    spmm_csr<64, true><<<(M + 15) / 16, 256, 0, stream>>>(rowptr, pairs, T, Hbuf, M);

    // layer 3: Hbuf @ W2 -> T ; spmm -> out
    gemm_f32<64, 32, 16, 4, 4><<<(M + 63) / 64, 128, 0, stream>>>(Hbuf, W2, T, M, HD2, OUT_DIM);
    spmm_csr<32, false><<<(M + 31) / 32, 256, 0, stream>>>(rowptr, pairs, T, out, M);
}

// Round 2
// 684.086 us; speedup vs baseline: 1.2258x; 1.2258x over previous
//
#include <hip/hip_runtime.h>

// GCN forward: l2norm -> [GEMM -> SpMM -> ReLU] x3 (last layer no ReLU)
// CSR built on-device each call (histogram + hierarchical scan + scatter), gather-SpMM.

constexpr int IN_DIM = 256, HD1 = 128, HD2 = 64, OUT_DIM = 32;
constexpr int SCAN_CHUNK = 2048;  // elements per block in hierarchical scan (256 thr x 8)

// ---------------- L2 normalize (one wave per row, float4 per lane) ----------------
__global__ __launch_bounds__(256) void l2norm_kernel(const float* __restrict__ in,
                                                     float* __restrict__ out, int M) {
    int wave = threadIdx.x >> 6;
    int lane = threadIdx.x & 63;
    int row = blockIdx.x * 4 + wave;
    if (row >= M) return;
    const float4 v = *reinterpret_cast<const float4*>(&in[(size_t)row * IN_DIM + lane * 4]);
    float s = v.x * v.x + v.y * v.y + v.z * v.z + v.w * v.w;
    #pragma unroll
    for (int off = 32; off; off >>= 1) s += __shfl_xor(s, off, 64);
    float scale = 1.0f / sqrtf(fmaxf(s, 1e-12f));
    float4 o{v.x * scale, v.y * scale, v.z * scale, v.w * scale};
    *reinterpret_cast<float4*>(&out[(size_t)row * IN_DIM + lane * 4]) = o;
}

// ---------------- CSR build ----------------
__global__ __launch_bounds__(256) void hist_kernel(const int* __restrict__ row,
                                                   int* __restrict__ counts, int E) {
    int e = blockIdx.x * blockDim.x + threadIdx.x;
    if (e < E) atomicAdd(&counts[row[e]], 1);
}

// pass 1: per-block sum of a 2048-element chunk of counts
__global__ __launch_bounds__(256) void scan_partial(const int* __restrict__ counts,
                                                    int* __restrict__ bsum, int n) {
    __shared__ int sm[256];
    const int tid = threadIdx.x;
    const int base = blockIdx.x * SCAN_CHUNK + tid * 8;
    int s = 0;
    #pragma unroll
    for (int i = 0; i < 8; ++i) {
        int idx = base + i;
        if (idx < n) s += counts[idx];
    }
    sm[tid] = s;
    __syncthreads();
    #pragma unroll
    for (int off = 128; off; off >>= 1) {
        if (tid < off) sm[tid] += sm[tid + off];
        __syncthreads();
    }
    if (tid == 0) bsum[blockIdx.x] = sm[0];
}

// pass 2: single-block exclusive scan of block sums (nblk <= 256), boff[nblk] = total
__global__ __launch_bounds__(256) void scan_blocksums(const int* __restrict__ bsum,
                                                      int* __restrict__ boff, int nblk) {
    __shared__ int sm[256];
    const int tid = threadIdx.x;
    int v = (tid < nblk) ? bsum[tid] : 0;
    sm[tid] = v;
    __syncthreads();
    #pragma unroll
    for (int off = 1; off < 256; off <<= 1) {
        int t = (tid >= off) ? sm[tid - off] : 0;
        __syncthreads();
        sm[tid] += t;
        __syncthreads();
    }
    if (tid < nblk) boff[tid] = sm[tid] - v;   // exclusive
    if (tid == 255) boff[nblk] = sm[255];      // grand total
}

// pass 3: per-block exclusive scan with global offset -> row_ptr
__global__ __launch_bounds__(256) void scan_final(const int* __restrict__ counts,
                                                  const int* __restrict__ boff,
                                                  int* __restrict__ row_ptr, int n, int nblk) {
    __shared__ int sm[256];
    const int tid = threadIdx.x;
    const int base = blockIdx.x * SCAN_CHUNK + tid * 8;
    int c[8];
    int s = 0;
    #pragma unroll
    for (int i = 0; i < 8; ++i) {
        int idx = base + i;
        c[i] = (idx < n) ? counts[idx] : 0;
        s += c[i];
    }
    sm[tid] = s;
    __syncthreads();
    #pragma unroll
    for (int off = 1; off < 256; off <<= 1) {
        int t = (tid >= off) ? sm[tid - off] : 0;
        __syncthreads();
        sm[tid] += t;
        __syncthreads();
    }
    int run = boff[blockIdx.x] + sm[tid] - s;  // exclusive prefix for this thread's 8
    #pragma unroll
    for (int i = 0; i < 8; ++i) {
        int idx = base + i;
        if (idx < n) row_ptr[idx] = run;
        run += c[i];
    }
    if (blockIdx.x == 0 && tid == 0) row_ptr[n] = boff[nblk];
}

__global__ __launch_bounds__(256) void scatter_kernel(const int* __restrict__ row,
                                                      const int* __restrict__ col,
                                                      const float* __restrict__ val,
                                                      const int* __restrict__ row_ptr,
                                                      int* __restrict__ row_cur,
                                                      int2* __restrict__ pairs, int E) {
    int e = blockIdx.x * blockDim.x + threadIdx.x;
    if (e < E) {
        int r = row[e];
        int pos = row_ptr[r] + atomicAdd(&row_cur[r], 1);
        pairs[pos] = make_int2(col[e], __float_as_int(val[e]));
    }
}

// ---------------- fp32 register-tiled GEMM: C[M,N] = A[M,K] @ B[K,N] ----------------
template <int BM, int BN, int BK, int TM, int TN>
__global__ __launch_bounds__((BM / TM) * (BN / TN)) void gemm_f32(
    const float* __restrict__ A, const float* __restrict__ B, float* __restrict__ C,
    int M, int K, int N) {
    constexpr int THREADS = (BM / TM) * (BN / TN);
    __shared__ float As[BK][BM + 4];
    __shared__ float Bs[BK][BN + 4];
    const int tid = threadIdx.x;
    const int tcol = tid % (BN / TN);
    const int trow = tid / (BN / TN);
    const int row0 = blockIdx.x * BM;
    float acc[TM][TN] = {};
    for (int k0 = 0; k0 < K; k0 += BK) {
        for (int i = tid * 4; i < BM * BK; i += THREADS * 4) {
            int m = i / BK, k = i % BK;
            float4 v = {0.f, 0.f, 0.f, 0.f};
            if (row0 + m < M)
                v = *reinterpret_cast<const float4*>(&A[(size_t)(row0 + m) * K + k0 + k]);
            As[k + 0][m] = v.x; As[k + 1][m] = v.y; As[k + 2][m] = v.z; As[k + 3][m] = v.w;
        }
        for (int i = tid * 4; i < BK * BN; i += THREADS * 4) {
            int k = i / BN, n = i % BN;
            *reinterpret_cast<float4*>(&Bs[k][n]) =
                *reinterpret_cast<const float4*>(&B[(size_t)(k0 + k) * N + n]);
        }
        __syncthreads();
        #pragma unroll
        for (int k = 0; k < BK; ++k) {
            float a[TM], b[TN];
            #pragma unroll
            for (int i = 0; i < TM; i += 4)
                *reinterpret_cast<float4*>(&a[i]) =
                    *reinterpret_cast<const float4*>(&As[k][trow * TM + i]);
            #pragma unroll
            for (int j = 0; j < TN; j += 4)
                *reinterpret_cast<float4*>(&b[j]) =
                    *reinterpret_cast<const float4*>(&Bs[k][tcol * TN + j]);
            #pragma unroll
            for (int i = 0; i < TM; ++i)
                #pragma unroll
                for (int j = 0; j < TN; ++j) acc[i][j] = fmaf(a[i], b[j], acc[i][j]);
        }
        __syncthreads();
    }
    #pragma unroll
    for (int i = 0; i < TM; ++i) {
        int r = row0 + trow * TM + i;
        if (r < M) {
            #pragma unroll
            for (int j = 0; j < TN; j += 4)
                *reinterpret_cast<float4*>(&C[(size_t)r * N + tcol * TN + j]) =
                    *reinterpret_cast<const float4*>(&acc[i][j]);
        }
    }
}

// ---------------- CSR SpMM: out[r,:] = sum_j val_j * H[col_j,:], optional ReLU ----------------
template <int D, bool RELU>
__global__ __launch_bounds__(256) void spmm_csr(const int* __restrict__ row_ptr,
                                                const int2* __restrict__ pairs,
                                                const float* __restrict__ H,
                                                float* __restrict__ out, int M) {
    constexpr int TPR = D / 4;                 // threads per row (float4 each)
    const int rpb = 256 / TPR;                 // rows per block
    const int lg = threadIdx.x % TPR;
    const int rloc = threadIdx.x / TPR;
    int r = blockIdx.x * rpb + rloc;
    if (r >= M) return;
    const int jb = row_ptr[r], je = row_ptr[r + 1];
    float4 acc = {0.f, 0.f, 0.f, 0.f};
    for (int j = jb; j < je; ++j) {
        int2 p = pairs[j];
        float v = __int_as_float(p.y);
        const float4 h = *reinterpret_cast<const float4*>(&H[(size_t)p.x * D + lg * 4]);
        acc.x = fmaf(v, h.x, acc.x);
        acc.y = fmaf(v, h.y, acc.y);
        acc.z = fmaf(v, h.z, acc.z);
        acc.w = fmaf(v, h.w, acc.w);
    }
    if (RELU) {
        acc.x = fmaxf(acc.x, 0.f); acc.y = fmaxf(acc.y, 0.f);
        acc.z = fmaxf(acc.z, 0.f); acc.w = fmaxf(acc.w, 0.f);
    }
    *reinterpret_cast<float4*>(&out[(size_t)r * D + lg * 4]) = acc;
}

extern "C" void kernel_launch(void* const* d_in, const int* in_sizes, int n_in,
                              void* d_out, int out_size, void* d_ws, size_t ws_size,
                              hipStream_t stream) {
    const float* features  = (const float*)d_in[0];
    const float* edge_vals = (const float*)d_in[1];
    const float* W0        = (const float*)d_in[2];
    const float* W1        = (const float*)d_in[3];
    const float* W2        = (const float*)d_in[4];
    const int*   edge_row  = (const int*)d_in[5];
    const int*   edge_col  = (const int*)d_in[6];
    const int M = in_sizes[0] / IN_DIM;   // 100000
    const int E = in_sizes[1];            // 1600000

    char* ws = (char*)d_ws;
    size_t o = 0;
    auto alloc = [&](size_t bytes) {
        size_t r = o;
        o += (bytes + 1023) & ~(size_t)1023;
        return r;
    };
    float* X      = (float*)(ws + alloc((size_t)M * IN_DIM * 4));  // reused as H buffer
    float* T      = (float*)(ws + alloc((size_t)M * HD1 * 4));     // GEMM outputs
    size_t counts_off = alloc((size_t)M * 4);
    int*   counts = (int*)(ws + counts_off);
    int*   rowcur = (int*)(ws + alloc((size_t)M * 4));
    size_t rowptr_off = alloc((size_t)(M + 1) * 4);
    int*   rowptr = (int*)(ws + rowptr_off);
    int2*  pairs  = (int2*)(ws + alloc((size_t)E * 8));
    const int nblk_scan = (M + SCAN_CHUNK - 1) / SCAN_CHUNK;       // 49 for M=100000
    int*   bsum   = (int*)(ws + alloc((size_t)256 * 4));
    int*   boff   = (int*)(ws + alloc((size_t)257 * 4));
    float* Hbuf = X;
    float* out = (float*)d_out;
    (void)ws_size; (void)n_in; (void)out_size;

    // zero counts + rowcur (adjacent in layout)
    hipMemsetAsync(ws + counts_off, 0, rowptr_off - counts_off, stream);

    // CSR build
    hist_kernel<<<(E + 255) / 256, 256, 0, stream>>>(edge_row, counts, E);
    scan_partial<<<nblk_scan, 256, 0, stream>>>(counts, bsum, M);
    scan_blocksums<<<1, 256, 0, stream>>>(bsum, boff, nblk_scan);
    scan_final<<<nblk_scan, 256, 0, stream>>>(counts, boff, rowptr, M, nblk_scan);
    scatter_kernel<<<(E + 255) / 256, 256, 0, stream>>>(edge_row, edge_col, edge_vals,
                                                        rowptr, rowcur, pairs, E);

    // normalize
    l2norm_kernel<<<(M + 3) / 4, 256, 0, stream>>>(features, X, M);

    // layer 1: X @ W0 -> T ; spmm+relu -> Hbuf
    gemm_f32<64, 128, 16, 8, 4><<<(M + 63) / 64, 256, 0, stream>>>(X, W0, T, M, IN_DIM, HD1);
    spmm_csr<128, true><<<(M + 7) / 8, 256, 0, stream>>>(rowptr, pairs, T, Hbuf, M);

    // layer 2: Hbuf @ W1 -> T ; spmm+relu -> Hbuf
    gemm_f32<64, 64, 16, 4, 4><<<(M + 63) / 64, 256, 0, stream>>>(Hbuf, W1, T, M, HD1, HD2);
    spmm_csr<64, true><<<(M + 15) / 16, 256, 0, stream>>>(rowptr, pairs, T, Hbuf, M);

    // layer 3: Hbuf @ W2 -> T ; spmm -> out
    gemm_f32<64, 32, 16, 4, 4><<<(M + 63) / 64, 128, 0, stream>>>(Hbuf, W2, T, M, HD2, OUT_DIM);
    spmm_csr<32, false><<<(M + 31) / 32, 256, 0, stream>>>(rowptr, pairs, T, out, M);
}

// Round 7
// 604.384 us; speedup vs baseline: 1.3874x; 1.1319x over previous
//
#include <hip/hip_runtime.h>

// GCN forward: l2norm -> [GEMM -> SpMM -> ReLU] x3 (last layer no ReLU)
// CSR built on-device (histogram + hierarchical scan + scatter).
// GEMM outputs stored bf16 (T) to halve SpMM gather traffic; all accumulation fp32.

constexpr int IN_DIM = 256, HD1 = 128, HD2 = 64, OUT_DIM = 32;
constexpr int SCAN_CHUNK = 2048;

__device__ inline ushort f32_to_bf16(float x) {
    unsigned u = __float_as_uint(x);
    unsigned r = (u + 0x7fff + ((u >> 16) & 1)) >> 16;  // round-nearest-even
    return (ushort)r;
}

__device__ inline void unpack_bf16x2(unsigned u, float& lo, float& hi) {
    lo = __uint_as_float(u << 16);
    hi = __uint_as_float(u & 0xffff0000u);
}

// ---------------- L2 normalize (one wave per row, float4 per lane) ----------------
__global__ __launch_bounds__(256) void l2norm_kernel(const float* __restrict__ in,
                                                     float* __restrict__ out, int M) {
    int wave = threadIdx.x >> 6;
    int lane = threadIdx.x & 63;
    int row = blockIdx.x * 4 + wave;
    if (row >= M) return;
    const float4 v = *reinterpret_cast<const float4*>(&in[(size_t)row * IN_DIM + lane * 4]);
    float s = v.x * v.x + v.y * v.y + v.z * v.z + v.w * v.w;
    #pragma unroll
    for (int off = 32; off; off >>= 1) s += __shfl_xor(s, off, 64);
    float scale = 1.0f / sqrtf(fmaxf(s, 1e-12f));
    float4 o{v.x * scale, v.y * scale, v.z * scale, v.w * scale};
    *reinterpret_cast<float4*>(&out[(size_t)row * IN_DIM + lane * 4]) = o;
}

// ---------------- CSR build ----------------
__global__ __launch_bounds__(256) void hist_kernel(const int* __restrict__ row,
                                                   int* __restrict__ counts, int E) {
    int e = blockIdx.x * blockDim.x + threadIdx.x;
    if (e < E) atomicAdd(&counts[row[e]], 1);
}

__global__ __launch_bounds__(256) void scan_partial(const int* __restrict__ counts,
                                                    int* __restrict__ bsum, int n) {
    __shared__ int sm[256];
    const int tid = threadIdx.x;
    const int base = blockIdx.x * SCAN_CHUNK + tid * 8;
    int s = 0;
    #pragma unroll
    for (int i = 0; i < 8; ++i) {
        int idx = base + i;
        if (idx < n) s += counts[idx];
    }
    sm[tid] = s;
    __syncthreads();
    #pragma unroll
    for (int off = 128; off; off >>= 1) {
        if (tid < off) sm[tid] += sm[tid + off];
        __syncthreads();
    }
    if (tid == 0) bsum[blockIdx.x] = sm[0];
}

__global__ __launch_bounds__(256) void scan_blocksums(const int* __restrict__ bsum,
                                                      int* __restrict__ boff, int nblk) {
    __shared__ int sm[256];
    const int tid = threadIdx.x;
    int v = (tid < nblk) ? bsum[tid] : 0;
    sm[tid] = v;
    __syncthreads();
    #pragma unroll
    for (int off = 1; off < 256; off <<= 1) {
        int t = (tid >= off) ? sm[tid - off] : 0;
        __syncthreads();
        sm[tid] += t;
        __syncthreads();
    }
    if (tid < nblk) boff[tid] = sm[tid] - v;
    if (tid == 255) boff[nblk] = sm[255];
}

__global__ __launch_bounds__(256) void scan_final(const int* __restrict__ counts,
                                                  const int* __restrict__ boff,
                                                  int* __restrict__ row_ptr, int n, int nblk) {
    __shared__ int sm[256];
    const int tid = threadIdx.x;
    const int base = blockIdx.x * SCAN_CHUNK + tid * 8;
    int c[8];
    int s = 0;
    #pragma unroll
    for (int i = 0; i < 8; ++i) {
        int idx = base + i;
        c[i] = (idx < n) ? counts[idx] : 0;
        s += c[i];
    }
    sm[tid] = s;
    __syncthreads();
    #pragma unroll
    for (int off = 1; off < 256; off <<= 1) {
        int t = (tid >= off) ? sm[tid - off] : 0;
        __syncthreads();
        sm[tid] += t;
        __syncthreads();
    }
    int run = boff[blockIdx.x] + sm[tid] - s;
    #pragma unroll
    for (int i = 0; i < 8; ++i) {
        int idx = base + i;
        if (idx < n) row_ptr[idx] = run;
        run += c[i];
    }
    if (blockIdx.x == 0 && tid == 0) row_ptr[n] = boff[nblk];
}

__global__ __launch_bounds__(256) void scatter_kernel(const int* __restrict__ row,
                                                      const int* __restrict__ col,
                                                      const float* __restrict__ val,
                                                      const int* __restrict__ row_ptr,
                                                      int* __restrict__ row_cur,
                                                      int2* __restrict__ pairs, int E) {
    int e = blockIdx.x * blockDim.x + threadIdx.x;
    if (e < E) {
        int r = row[e];
        int pos = row_ptr[r] + atomicAdd(&row_cur[r], 1);
        pairs[pos] = make_int2(col[e], __float_as_int(val[e]));
    }
}

// ---------------- fp32 register-tiled GEMM, bf16 output: C[M,N] = A[M,K] @ B[K,N] ----------------
template <int BM, int BN, int BK, int TM, int TN>
__global__ __launch_bounds__((BM / TM) * (BN / TN)) void gemm_f32_bf16out(
    const float* __restrict__ A, const float* __restrict__ B, ushort* __restrict__ C,
    int M, int K, int N) {
    constexpr int THREADS = (BM / TM) * (BN / TN);
    __shared__ float As[BK][BM + 4];
    __shared__ float Bs[BK][BN + 4];
    const int tid = threadIdx.x;
    const int tcol = tid % (BN / TN);
    const int trow = tid / (BN / TN);
    const int row0 = blockIdx.x * BM;
    float acc[TM][TN] = {};
    for (int k0 = 0; k0 < K; k0 += BK) {
        for (int i = tid * 4; i < BM * BK; i += THREADS * 4) {
            int m = i / BK, k = i % BK;
            float4 v = {0.f, 0.f, 0.f, 0.f};
            if (row0 + m < M)
                v = *reinterpret_cast<const float4*>(&A[(size_t)(row0 + m) * K + k0 + k]);
            As[k + 0][m] = v.x; As[k + 1][m] = v.y; As[k + 2][m] = v.z; As[k + 3][m] = v.w;
        }
        for (int i = tid * 4; i < BK * BN; i += THREADS * 4) {
            int k = i / BN, n = i % BN;
            *reinterpret_cast<float4*>(&Bs[k][n]) =
                *reinterpret_cast<const float4*>(&B[(size_t)(k0 + k) * N + n]);
        }
        __syncthreads();
        #pragma unroll
        for (int k = 0; k < BK; ++k) {
            float a[TM], b[TN];
            #pragma unroll
            for (int i = 0; i < TM; i += 4)
                *reinterpret_cast<float4*>(&a[i]) =
                    *reinterpret_cast<const float4*>(&As[k][trow * TM + i]);
            #pragma unroll
            for (int j = 0; j < TN; j += 4)
                *reinterpret_cast<float4*>(&b[j]) =
                    *reinterpret_cast<const float4*>(&Bs[k][tcol * TN + j]);
            #pragma unroll
            for (int i = 0; i < TM; ++i)
                #pragma unroll
                for (int j = 0; j < TN; ++j) acc[i][j] = fmaf(a[i], b[j], acc[i][j]);
        }
        __syncthreads();
    }
    #pragma unroll
    for (int i = 0; i < TM; ++i) {
        int r = row0 + trow * TM + i;
        if (r < M) {
            #pragma unroll
            for (int j = 0; j < TN; j += 4) {
                uint2 pk;
                pk.x = (unsigned)f32_to_bf16(acc[i][j + 0]) |
                       ((unsigned)f32_to_bf16(acc[i][j + 1]) << 16);
                pk.y = (unsigned)f32_to_bf16(acc[i][j + 2]) |
                       ((unsigned)f32_to_bf16(acc[i][j + 3]) << 16);
                *reinterpret_cast<uint2*>(&C[(size_t)r * N + tcol * TN + j]) = pk;
            }
        }
    }
}

// ---------------- CSR SpMM, bf16 gather operand: out[r,:] = sum_j val_j * H[col_j,:] ----------------
template <int D, bool RELU>
__global__ __launch_bounds__(256) void spmm_bf16(const int* __restrict__ row_ptr,
                                                 const int2* __restrict__ pairs,
                                                 const ushort* __restrict__ H,
                                                 float* __restrict__ out, int M) {
    constexpr int TPR = D / 8;                 // threads per row, 8 bf16 (16B) per lane
    const int rpb = 256 / TPR;
    const int lg = threadIdx.x % TPR;
    const int rloc = threadIdx.x / TPR;
    int r = blockIdx.x * rpb + rloc;
    if (r >= M) return;
    const int jb = row_ptr[r], je = row_ptr[r + 1];
    float acc[8] = {};
    int j = jb;
    for (; j + 1 < je; j += 2) {               // unroll x2: two independent gathers in flight
        int2 p0 = pairs[j];
        int2 p1 = pairs[j + 1];
        uint4 u0 = *reinterpret_cast<const uint4*>(&H[(size_t)p0.x * D + lg * 8]);
        uint4 u1 = *reinterpret_cast<const uint4*>(&H[(size_t)p1.x * D + lg * 8]);
        float v0 = __int_as_float(p0.y), v1 = __int_as_float(p1.y);
        float f[8];
        unpack_bf16x2(u0.x, f[0], f[1]); unpack_bf16x2(u0.y, f[2], f[3]);
        unpack_bf16x2(u0.z, f[4], f[5]); unpack_bf16x2(u0.w, f[6], f[7]);
        #pragma unroll
        for (int i = 0; i < 8; ++i) acc[i] = fmaf(v0, f[i], acc[i]);
        unpack_bf16x2(u1.x, f[0], f[1]); unpack_bf16x2(u1.y, f[2], f[3]);
        unpack_bf16x2(u1.z, f[4], f[5]); unpack_bf16x2(u1.w, f[6], f[7]);
        #pragma unroll
        for (int i = 0; i < 8; ++i) acc[i] = fmaf(v1, f[i], acc[i]);
    }
    if (j < je) {
        int2 p0 = pairs[j];
        uint4 u0 = *reinterpret_cast<const uint4*>(&H[(size_t)p0.x * D + lg * 8]);
        float v0 = __int_as_float(p0.y);
        float f[8];
        unpack_bf16x2(u0.x, f[0], f[1]); unpack_bf16x2(u0.y, f[2], f[3]);
        unpack_bf16x2(u0.z, f[4], f[5]); unpack_bf16x2(u0.w, f[6], f[7]);
        #pragma unroll
        for (int i = 0; i < 8; ++i) acc[i] = fmaf(v0, f[i], acc[i]);
    }
    if (RELU) {
        #pragma unroll
        for (int i = 0; i < 8; ++i) acc[i] = fmaxf(acc[i], 0.f);
    }
    float* dst = &out[(size_t)r * D + lg * 8];
    *reinterpret_cast<float4*>(dst) = *reinterpret_cast<const float4*>(&acc[0]);
    *reinterpret_cast<float4*>(dst + 4) = *reinterpret_cast<const float4*>(&acc[4]);
}

extern "C" void kernel_launch(void* const* d_in, const int* in_sizes, int n_in,
                              void* d_out, int out_size, void* d_ws, size_t ws_size,
                              hipStream_t stream) {
    const float* features  = (const float*)d_in[0];
    const float* edge_vals = (const float*)d_in[1];
    const float* W0        = (const float*)d_in[2];
    const float* W1        = (const float*)d_in[3];
    const float* W2        = (const float*)d_in[4];
    const int*   edge_row  = (const int*)d_in[5];
    const int*   edge_col  = (const int*)d_in[6];
    const int M = in_sizes[0] / IN_DIM;   // 100000
    const int E = in_sizes[1];            // 1600000

    char* ws = (char*)d_ws;
    size_t o = 0;
    auto alloc = [&](size_t bytes) {
        size_t r = o;
        o += (bytes + 1023) & ~(size_t)1023;
        return r;
    };
    float*  X      = (float*)(ws + alloc((size_t)M * IN_DIM * 4));  // reused as H buffer (fp32)
    ushort* T      = (ushort*)(ws + alloc((size_t)M * HD1 * 2));    // GEMM outputs (bf16)
    size_t counts_off = alloc((size_t)M * 4);
    int*   counts = (int*)(ws + counts_off);
    int*   rowcur = (int*)(ws + alloc((size_t)M * 4));
    size_t rowptr_off = alloc((size_t)(M + 1) * 4);
    int*   rowptr = (int*)(ws + rowptr_off);
    int2*  pairs  = (int2*)(ws + alloc((size_t)E * 8));
    const int nblk_scan = (M + SCAN_CHUNK - 1) / SCAN_CHUNK;
    int*   bsum   = (int*)(ws + alloc((size_t)256 * 4));
    int*   boff   = (int*)(ws + alloc((size_t)257 * 4));
    float* Hbuf = X;
    float* out = (float*)d_out;
    (void)ws_size; (void)n_in; (void)out_size;

    hipMemsetAsync(ws + counts_off, 0, rowptr_off - counts_off, stream);

    // CSR build
    hist_kernel<<<(E + 255) / 256, 256, 0, stream>>>(edge_row, counts, E);
    scan_partial<<<nblk_scan, 256, 0, stream>>>(counts, bsum, M);
    scan_blocksums<<<1, 256, 0, stream>>>(bsum, boff, nblk_scan);
    scan_final<<<nblk_scan, 256, 0, stream>>>(counts, boff, rowptr, M, nblk_scan);
    scatter_kernel<<<(E + 255) / 256, 256, 0, stream>>>(edge_row, edge_col, edge_vals,
                                                        rowptr, rowcur, pairs, E);

    // normalize
    l2norm_kernel<<<(M + 3) / 4, 256, 0, stream>>>(features, X, M);

    // layer 1: X @ W0 -> T(bf16) ; spmm+relu -> Hbuf(fp32)
    gemm_f32_bf16out<64, 128, 16, 8, 4><<<(M + 63) / 64, 256, 0, stream>>>(X, W0, T, M, IN_DIM, HD1);
    spmm_bf16<128, true><<<(M + 15) / 16, 256, 0, stream>>>(rowptr, pairs, T, Hbuf, M);

    // layer 2
    gemm_f32_bf16out<64, 64, 16, 4, 4><<<(M + 63) / 64, 256, 0, stream>>>(Hbuf, W1, T, M, HD1, HD2);
    spmm_bf16<64, true><<<(M + 31) / 32, 256, 0, stream>>>(rowptr, pairs, T, Hbuf, M);

    // layer 3
    gemm_f32_bf16out<64, 32, 16, 4, 4><<<(M + 63) / 64, 128, 0, stream>>>(Hbuf, W2, T, M, HD2, OUT_DIM);
    spmm_bf16<32, false><<<(M + 63) / 64, 256, 0, stream>>>(rowptr, pairs, T, out, M);
}

// Round 8
// 496.957 us; speedup vs baseline: 1.6873x; 1.2162x over previous
//
#include <hip/hip_runtime.h>

// GCN forward: l2norm -> [GEMM -> SpMM -> ReLU] x3 (last layer no ReLU)
// CSR built on-device (histogram + hierarchical scan + scatter).
// GEMMs on bf16 MFMA (16x16x32, fp32 accum), A/B staged via global_load_lds
// with pre-swizzled global source (XOR (row&7)<<4) for conflict-free ds_read_b128.
// X, H, T, W all bf16; SpMM accumulates fp32; final output fp32.

constexpr int IN_DIM = 256, HD1 = 128, HD2 = 64, OUT_DIM = 32;
constexpr int SCAN_CHUNK = 2048;

typedef __bf16 bf16x8 __attribute__((ext_vector_type(8)));
typedef float f32x4 __attribute__((ext_vector_type(4)));

__device__ inline ushort f32_to_bf16(float x) {
    unsigned u = __float_as_uint(x);
    unsigned r = (u + 0x7fff + ((u >> 16) & 1)) >> 16;  // round-nearest-even
    return (ushort)r;
}

__device__ inline void unpack_bf16x2(unsigned u, float& lo, float& hi) {
    lo = __uint_as_float(u << 16);
    hi = __uint_as_float(u & 0xffff0000u);
}

// ---------------- L2 normalize -> bf16 X (one wave per row) ----------------
__global__ __launch_bounds__(256) void l2norm_kernel(const float* __restrict__ in,
                                                     ushort* __restrict__ out, int M) {
    int wave = threadIdx.x >> 6;
    int lane = threadIdx.x & 63;
    int row = blockIdx.x * 4 + wave;
    if (row >= M) return;
    const float4 v = *reinterpret_cast<const float4*>(&in[(size_t)row * IN_DIM + lane * 4]);
    float s = v.x * v.x + v.y * v.y + v.z * v.z + v.w * v.w;
    #pragma unroll
    for (int off = 32; off; off >>= 1) s += __shfl_xor(s, off, 64);
    float scale = 1.0f / sqrtf(fmaxf(s, 1e-12f));
    uint2 pk;
    pk.x = (unsigned)f32_to_bf16(v.x * scale) | ((unsigned)f32_to_bf16(v.y * scale) << 16);
    pk.y = (unsigned)f32_to_bf16(v.z * scale) | ((unsigned)f32_to_bf16(v.w * scale) << 16);
    *reinterpret_cast<uint2*>(&out[(size_t)row * IN_DIM + lane * 4]) = pk;
}

// ---------------- weight transpose + bf16: WT[n][k] = W[k][n] ----------------
__global__ __launch_bounds__(256) void wt_kernel(const float* __restrict__ W,
                                                 ushort* __restrict__ WT, int K, int N) {
    int idx = blockIdx.x * 256 + threadIdx.x;
    if (idx < K * N) {
        int k = idx / N, n = idx % N;
        WT[(size_t)n * K + k] = f32_to_bf16(W[idx]);
    }
}

// ---------------- CSR build ----------------
__global__ __launch_bounds__(256) void hist_kernel(const int* __restrict__ row,
                                                   int* __restrict__ counts, int E) {
    int e = blockIdx.x * blockDim.x + threadIdx.x;
    if (e < E) atomicAdd(&counts[row[e]], 1);
}

__global__ __launch_bounds__(256) void scan_partial(const int* __restrict__ counts,
                                                    int* __restrict__ bsum, int n) {
    __shared__ int sm[256];
    const int tid = threadIdx.x;
    const int base = blockIdx.x * SCAN_CHUNK + tid * 8;
    int s = 0;
    #pragma unroll
    for (int i = 0; i < 8; ++i) {
        int idx = base + i;
        if (idx < n) s += counts[idx];
    }
    sm[tid] = s;
    __syncthreads();
    #pragma unroll
    for (int off = 128; off; off >>= 1) {
        if (tid < off) sm[tid] += sm[tid + off];
        __syncthreads();
    }
    if (tid == 0) bsum[blockIdx.x] = sm[0];
}

__global__ __launch_bounds__(256) void scan_blocksums(const int* __restrict__ bsum,
                                                      int* __restrict__ boff, int nblk) {
    __shared__ int sm[256];
    const int tid = threadIdx.x;
    int v = (tid < nblk) ? bsum[tid] : 0;
    sm[tid] = v;
    __syncthreads();
    #pragma unroll
    for (int off = 1; off < 256; off <<= 1) {
        int t = (tid >= off) ? sm[tid - off] : 0;
        __syncthreads();
        sm[tid] += t;
        __syncthreads();
    }
    if (tid < nblk) boff[tid] = sm[tid] - v;
    if (tid == 255) boff[nblk] = sm[255];
}

__global__ __launch_bounds__(256) void scan_final(const int* __restrict__ counts,
                                                  const int* __restrict__ boff,
                                                  int* __restrict__ row_ptr, int n, int nblk) {
    __shared__ int sm[256];
    const int tid = threadIdx.x;
    const int base = blockIdx.x * SCAN_CHUNK + tid * 8;
    int c[8];
    int s = 0;
    #pragma unroll
    for (int i = 0; i < 8; ++i) {
        int idx = base + i;
        c[i] = (idx < n) ? counts[idx] : 0;
        s += c[i];
    }
    sm[tid] = s;
    __syncthreads();
    #pragma unroll
    for (int off = 1; off < 256; off <<= 1) {
        int t = (tid >= off) ? sm[tid - off] : 0;
        __syncthreads();
        sm[tid] += t;
        __syncthreads();
    }
    int run = boff[blockIdx.x] + sm[tid] - s;
    #pragma unroll
    for (int i = 0; i < 8; ++i) {
        int idx = base + i;
        if (idx < n) row_ptr[idx] = run;
        run += c[i];
    }
    if (blockIdx.x == 0 && tid == 0) row_ptr[n] = boff[nblk];
}

__global__ __launch_bounds__(256) void scatter_kernel(const int* __restrict__ row,
                                                      const int* __restrict__ col,
                                                      const float* __restrict__ val,
                                                      const int* __restrict__ row_ptr,
                                                      int* __restrict__ row_cur,
                                                      int2* __restrict__ pairs, int E) {
    int e = blockIdx.x * blockDim.x + threadIdx.x;
    if (e < E) {
        int r = row[e];
        int pos = row_ptr[r] + atomicAdd(&row_cur[r], 1);
        pairs[pos] = make_int2(col[e], __float_as_int(val[e]));
    }
}

// ---------------- bf16 MFMA GEMM: C[Mp,BN] = A[Mp,K] @ BT[BN,K]^T ----------------
// BM=128 rows/block, BK=64, 4 waves (WM x WN). LDS rows are 128B (64 bf16) with
// XOR swizzle ((row&7)<<4) applied on the GLOBAL source (staging) and on ds_read.
template <int BN, int WM, int WN>
__global__ __launch_bounds__(256) void gemm_bf16_mfma(
    const ushort* __restrict__ A, const ushort* __restrict__ BT,
    ushort* __restrict__ C, int K) {
    constexpr int BM = 128, BK = 64;
    constexpr int FM = BM / WM / 16;
    constexpr int FN = BN / WN / 16;
    __shared__ ushort As[BM * BK];
    __shared__ ushort Bs[BN * BK];
    const int tid = threadIdx.x;
    const int lane = tid & 63;
    const int wid = tid >> 6;
    const int wm = wid / WN;
    const int wn = wid % WN;
    const int row0 = blockIdx.x * BM;
    const size_t strideB = (size_t)K * 2;  // bytes per row of A and BT

    f32x4 acc[FM][FN] = {};

    // reader lane offset within a 16-row x 64-col subtile (bytes), swizzled
    const int lkb = ((lane >> 4) << 4) ^ ((lane & 7) << 4);
    const int laneOff = (lane & 15) * 128 + lkb;

    for (int k0 = 0; k0 < K; k0 += BK) {
        // ---- stage A tile (BM rows) ----
        {
            constexpr int per_wave = BM * 128 / 4;
            const char* gbase = (const char*)(A + (size_t)row0 * K);
            #pragma unroll
            for (int i = 0; i < per_wave / 1024; ++i) {
                int o = wid * per_wave + i * 1024 + lane * 16;
                int row = o >> 7;
                int kb = (o & 127) ^ ((row & 7) << 4);
                const char* src = gbase + (size_t)row * strideB + (size_t)k0 * 2 + kb;
                ushort* dst = As + (wid * per_wave + i * 1024) / 2;
                __builtin_amdgcn_global_load_lds(
                    (const __attribute__((address_space(1))) unsigned int*)src,
                    (__attribute__((address_space(3))) unsigned int*)dst, 16, 0, 0);
            }
        }
        // ---- stage B tile (BN rows) ----
        {
            constexpr int per_wave = BN * 128 / 4;
            const char* gbase = (const char*)BT;
            #pragma unroll
            for (int i = 0; i < per_wave / 1024; ++i) {
                int o = wid * per_wave + i * 1024 + lane * 16;
                int row = o >> 7;
                int kb = (o & 127) ^ ((row & 7) << 4);
                const char* src = gbase + (size_t)row * strideB + (size_t)k0 * 2 + kb;
                ushort* dst = Bs + (wid * per_wave + i * 1024) / 2;
                __builtin_amdgcn_global_load_lds(
                    (const __attribute__((address_space(1))) unsigned int*)src,
                    (__attribute__((address_space(3))) unsigned int*)dst, 16, 0, 0);
            }
        }
        __syncthreads();

        #pragma unroll
        for (int w = 0; w < BK / 32; ++w) {
            bf16x8 af[FM], bfr[FN];
            #pragma unroll
            for (int mi = 0; mi < FM; ++mi) {
                int byte = wm * FM * 2048 + mi * 2048 + (laneOff ^ (w << 6));
                af[mi] = *(const bf16x8*)((const char*)As + byte);
            }
            #pragma unroll
            for (int ni = 0; ni < FN; ++ni) {
                int byte = wn * FN * 2048 + ni * 2048 + (laneOff ^ (w << 6));
                bfr[ni] = *(const bf16x8*)((const char*)Bs + byte);
            }
            #pragma unroll
            for (int mi = 0; mi < FM; ++mi)
                #pragma unroll
                for (int ni = 0; ni < FN; ++ni)
                    acc[mi][ni] = __builtin_amdgcn_mfma_f32_16x16x32_bf16(
                        af[mi], bfr[ni], acc[mi][ni], 0, 0, 0);
        }
        __syncthreads();
    }

    // ---- store C (bf16), C/D layout: col=lane&15, row=(lane>>4)*4+r ----
    #pragma unroll
    for (int mi = 0; mi < FM; ++mi) {
        #pragma unroll
        for (int ni = 0; ni < FN; ++ni) {
            int rbase = row0 + wm * FM * 16 + mi * 16 + ((lane >> 4) << 2);
            int col = wn * FN * 16 + ni * 16 + (lane & 15);
            #pragma unroll
            for (int r = 0; r < 4; ++r)
                C[(size_t)(rbase + r) * BN + col] = f32_to_bf16(acc[mi][ni][r]);
        }
    }
}

// ---------------- CSR SpMM, bf16 gather: out[r,:] = sum_j val_j * H[col_j,:] ----------------
template <int D, bool RELU, bool OUTF32>
__global__ __launch_bounds__(256) void spmm_bf16(const int* __restrict__ row_ptr,
                                                 const int2* __restrict__ pairs,
                                                 const ushort* __restrict__ H,
                                                 void* __restrict__ outp, int M) {
    constexpr int TPR = D / 8;                 // threads per row, 8 bf16 (16B) per lane
    const int rpb = 256 / TPR;
    const int lg = threadIdx.x % TPR;
    const int rloc = threadIdx.x / TPR;
    int r = blockIdx.x * rpb + rloc;
    if (r >= M) return;
    const int jb = row_ptr[r], je = row_ptr[r + 1];
    float acc[8] = {};
    int j = jb;
    for (; j + 1 < je; j += 2) {               // two independent gathers in flight
        int2 p0 = pairs[j];
        int2 p1 = pairs[j + 1];
        uint4 u0 = *reinterpret_cast<const uint4*>(&H[(size_t)p0.x * D + lg * 8]);
        uint4 u1 = *reinterpret_cast<const uint4*>(&H[(size_t)p1.x * D + lg * 8]);
        float v0 = __int_as_float(p0.y), v1 = __int_as_float(p1.y);
        float f[8];
        unpack_bf16x2(u0.x, f[0], f[1]); unpack_bf16x2(u0.y, f[2], f[3]);
        unpack_bf16x2(u0.z, f[4], f[5]); unpack_bf16x2(u0.w, f[6], f[7]);
        #pragma unroll
        for (int i = 0; i < 8; ++i) acc[i] = fmaf(v0, f[i], acc[i]);
        unpack_bf16x2(u1.x, f[0], f[1]); unpack_bf16x2(u1.y, f[2], f[3]);
        unpack_bf16x2(u1.z, f[4], f[5]); unpack_bf16x2(u1.w, f[6], f[7]);
        #pragma unroll
        for (int i = 0; i < 8; ++i) acc[i] = fmaf(v1, f[i], acc[i]);
    }
    if (j < je) {
        int2 p0 = pairs[j];
        uint4 u0 = *reinterpret_cast<const uint4*>(&H[(size_t)p0.x * D + lg * 8]);
        float v0 = __int_as_float(p0.y);
        float f[8];
        unpack_bf16x2(u0.x, f[0], f[1]); unpack_bf16x2(u0.y, f[2], f[3]);
        unpack_bf16x2(u0.z, f[4], f[5]); unpack_bf16x2(u0.w, f[6], f[7]);
        #pragma unroll
        for (int i = 0; i < 8; ++i) acc[i] = fmaf(v0, f[i], acc[i]);
    }
    if (RELU) {
        #pragma unroll
        for (int i = 0; i < 8; ++i) acc[i] = fmaxf(acc[i], 0.f);
    }
    if (OUTF32) {
        float* dst = (float*)outp + (size_t)r * D + lg * 8;
        *reinterpret_cast<float4*>(dst) = *reinterpret_cast<const float4*>(&acc[0]);
        *reinterpret_cast<float4*>(dst + 4) = *reinterpret_cast<const float4*>(&acc[4]);
    } else {
        uint4 pk;
        pk.x = (unsigned)f32_to_bf16(acc[0]) | ((unsigned)f32_to_bf16(acc[1]) << 16);
        pk.y = (unsigned)f32_to_bf16(acc[2]) | ((unsigned)f32_to_bf16(acc[3]) << 16);
        pk.z = (unsigned)f32_to_bf16(acc[4]) | ((unsigned)f32_to_bf16(acc[5]) << 16);
        pk.w = (unsigned)f32_to_bf16(acc[6]) | ((unsigned)f32_to_bf16(acc[7]) << 16);
        *reinterpret_cast<uint4*>((ushort*)outp + (size_t)r * D + lg * 8) = pk;
    }
}

extern "C" void kernel_launch(void* const* d_in, const int* in_sizes, int n_in,
                              void* d_out, int out_size, void* d_ws, size_t ws_size,
                              hipStream_t stream) {
    const float* features  = (const float*)d_in[0];
    const float* edge_vals = (const float*)d_in[1];
    const float* W0        = (const float*)d_in[2];
    const float* W1        = (const float*)d_in[3];
    const float* W2        = (const float*)d_in[4];
    const int*   edge_row  = (const int*)d_in[5];
    const int*   edge_col  = (const int*)d_in[6];
    const int M = in_sizes[0] / IN_DIM;     // 100000
    const int E = in_sizes[1];              // 1600000
    const int Mp = ((M + 127) / 128) * 128; // 100096, padded for GEMM tiles

    char* ws = (char*)d_ws;
    size_t o = 0;
    auto alloc = [&](size_t bytes) {
        size_t r = o;
        o += (bytes + 1023) & ~(size_t)1023;
        return r;
    };
    ushort* XH    = (ushort*)(ws + alloc((size_t)Mp * IN_DIM * 2));  // X, then reused as H
    ushort* T     = (ushort*)(ws + alloc((size_t)Mp * HD1 * 2));     // GEMM outputs (bf16)
    size_t counts_off = alloc((size_t)M * 4);
    int*   counts = (int*)(ws + counts_off);
    int*   rowcur = (int*)(ws + alloc((size_t)M * 4));
    size_t rowptr_off = alloc((size_t)(M + 1) * 4);
    int*   rowptr = (int*)(ws + rowptr_off);
    int2*  pairs  = (int2*)(ws + alloc((size_t)E * 8));
    const int nblk_scan = (M + SCAN_CHUNK - 1) / SCAN_CHUNK;
    int*   bsum   = (int*)(ws + alloc((size_t)256 * 4));
    int*   boff   = (int*)(ws + alloc((size_t)257 * 4));
    ushort* W0T   = (ushort*)(ws + alloc((size_t)HD1 * IN_DIM * 2));
    ushort* W1T   = (ushort*)(ws + alloc((size_t)HD2 * HD1 * 2));
    ushort* W2T   = (ushort*)(ws + alloc((size_t)OUT_DIM * HD2 * 2));
    float* out = (float*)d_out;
    (void)ws_size; (void)n_in; (void)out_size;

    hipMemsetAsync(ws + counts_off, 0, rowptr_off - counts_off, stream);

    // CSR build
    hist_kernel<<<(E + 255) / 256, 256, 0, stream>>>(edge_row, counts, E);
    scan_partial<<<nblk_scan, 256, 0, stream>>>(counts, bsum, M);
    scan_blocksums<<<1, 256, 0, stream>>>(bsum, boff, nblk_scan);
    scan_final<<<nblk_scan, 256, 0, stream>>>(counts, boff, rowptr, M, nblk_scan);
    scatter_kernel<<<(E + 255) / 256, 256, 0, stream>>>(edge_row, edge_col, edge_vals,
                                                        rowptr, rowcur, pairs, E);

    // weights -> bf16 transposed
    wt_kernel<<<(IN_DIM * HD1 + 255) / 256, 256, 0, stream>>>(W0, W0T, IN_DIM, HD1);
    wt_kernel<<<(HD1 * HD2 + 255) / 256, 256, 0, stream>>>(W1, W1T, HD1, HD2);
    wt_kernel<<<(HD2 * OUT_DIM + 255) / 256, 256, 0, stream>>>(W2, W2T, HD2, OUT_DIM);

    // normalize -> bf16 X
    l2norm_kernel<<<(M + 3) / 4, 256, 0, stream>>>(features, XH, M);

    const int gblk = Mp / 128;  // 782

    // layer 1: X[Mp,256] @ W0 -> T[Mp,128] ; spmm+relu -> H[Mp,128] (bf16, in XH)
    gemm_bf16_mfma<128, 2, 2><<<gblk, 256, 0, stream>>>(XH, W0T, T, IN_DIM);
    spmm_bf16<128, true, false><<<(M + 15) / 16, 256, 0, stream>>>(rowptr, pairs, T, XH, M);

    // layer 2: H[Mp,128] @ W1 -> T[Mp,64] ; spmm+relu -> H[Mp,64]
    gemm_bf16_mfma<64, 2, 2><<<gblk, 256, 0, stream>>>(XH, W1T, T, HD1);
    spmm_bf16<64, true, false><<<(M + 31) / 32, 256, 0, stream>>>(rowptr, pairs, T, XH, M);

    // layer 3: H[Mp,64] @ W2 -> T[Mp,32] ; spmm -> out (fp32)
    gemm_bf16_mfma<32, 4, 1><<<gblk, 256, 0, stream>>>(XH, W2T, T, HD2);
    spmm_bf16<32, false, true><<<(M + 63) / 64, 256, 0, stream>>>(rowptr, pairs, T, out, M);
}